// Round 1
// baseline (1136.401 us; speedup 1.0000x reference)
//
#include <hip/hip_runtime.h>
#include <hip/hip_bf16.h>
#include <cstdint>

typedef unsigned short u16;
typedef u16  u16x8 __attribute__((ext_vector_type(8)));
typedef short s16x8 __attribute__((ext_vector_type(8)));
typedef float f32x4 __attribute__((ext_vector_type(4)));

#define PI_F 3.14159265358979323846f

static __device__ __forceinline__ u16 f2bf(float f) {
    union { float f; unsigned u; } v; v.f = f;
    unsigned r = v.u + 0x7fffu + ((v.u >> 16) & 1u);
    return (u16)(r >> 16);
}
static __device__ __forceinline__ float bf2f(u16 h) {
    union { unsigned u; float f; } v; v.u = ((unsigned)h) << 16;
    return v.f;
}

// ---------------------------------------------------------------------------
// Expand quaternion weight W[4][512][in_q] into real matrix E[2048][4*in_q] bf16
// E[4o+c][4i+c'] = sign(c,c') * W[comp(c,c')][o][i]
// ---------------------------------------------------------------------------
__global__ void build_E(const float* __restrict__ W, u16* __restrict__ E, int logK) {
    const int K = 1 << logK;
    int idx = blockIdx.x * 256 + threadIdx.x;
    if (idx >= (2048 << logK)) return;
    int n = idx >> logK, k = idx & (K - 1);
    int o = n >> 2, c = n & 3, i = k >> 2, cp = k & 3;
    const int   qm[4][4] = {{0,1,2,3},{1,0,3,2},{2,3,0,1},{3,2,1,0}};
    const float qs[4][4] = {{1.f,-1.f,-1.f,-1.f},{1.f,1.f,1.f,-1.f},
                            {1.f,-1.f,1.f,1.f},{1.f,1.f,-1.f,1.f}};
    int in_q = K >> 2;
    float w = W[(size_t)qm[c][cp] * 512 * in_q + (size_t)o * in_q + i] * qs[c][cp];
    E[idx] = f2bf(w);
}

// ---------------------------------------------------------------------------
// bf16 MFMA GEMM: out[M=8192][N=2048] = A[M][K] * E[N][K]^T + bias[N]
// 64x64 block tile, BK=32, 4 waves (each 16 rows x 64 cols), 16x16x32 MFMA.
// OUTMODE 0: bf16 natural [m][n];  1: f32 natural (d_out);
//         2: bf16 transposed [b][n][s]  (m = b*2048+s)
// ---------------------------------------------------------------------------
template<int K, bool AF32, int OUTMODE>
__global__ __launch_bounds__(256) void gemm_k(const void* __restrict__ Ap,
                                              const u16* __restrict__ E,
                                              const float* __restrict__ bias,
                                              void* __restrict__ outp) {
    __shared__ u16 As[64][40];   // +8 pad: row stride 80B breaks bank conflicts
    __shared__ u16 Bs[64][40];
    const int t    = threadIdx.x;
    const int m0   = blockIdx.y * 64;
    const int n0   = blockIdx.x * 64;
    const int row  = t >> 2;
    const int cg   = (t & 3) * 8;
    const int lane = t & 63, wave = t >> 6;
    const int lr   = lane & 15, kg = lane >> 4;

    f32x4 acc[4];
#pragma unroll
    for (int i = 0; i < 4; ++i) acc[i] = (f32x4){0.f, 0.f, 0.f, 0.f};

    for (int k0 = 0; k0 < K; k0 += 32) {
        if constexpr (AF32) {
            const float* ap = (const float*)Ap + (size_t)(m0 + row) * K + k0 + cg;
            float4 a0 = *(const float4*)ap;
            float4 a1 = *(const float4*)(ap + 4);
            u16* dst = &As[row][cg];
            dst[0] = f2bf(a0.x); dst[1] = f2bf(a0.y); dst[2] = f2bf(a0.z); dst[3] = f2bf(a0.w);
            dst[4] = f2bf(a1.x); dst[5] = f2bf(a1.y); dst[6] = f2bf(a1.z); dst[7] = f2bf(a1.w);
        } else {
            const u16* ap = (const u16*)Ap + (size_t)(m0 + row) * K + k0 + cg;
            *(u16x8*)&As[row][cg] = *(const u16x8*)ap;
        }
        const u16* bp = E + (size_t)(n0 + row) * K + k0 + cg;
        *(u16x8*)&Bs[row][cg] = *(const u16x8*)bp;
        __syncthreads();

        s16x8 a = *(const s16x8*)&As[wave * 16 + lr][kg * 8];
#pragma unroll
        for (int nn = 0; nn < 4; ++nn) {
            s16x8 b = *(const s16x8*)&Bs[nn * 16 + lr][kg * 8];
            acc[nn] = __builtin_amdgcn_mfma_f32_16x16x32_bf16(a, b, acc[nn], 0, 0, 0);
        }
        __syncthreads();
    }

#pragma unroll
    for (int nn = 0; nn < 4; ++nn) {
        int n = n0 + nn * 16 + lr;
        float bv = bias[n];
#pragma unroll
        for (int r = 0; r < 4; ++r) {
            int m = m0 + wave * 16 + kg * 4 + r;
            float val = acc[nn][r] + bv;
            if constexpr (OUTMODE == 0) {
                ((u16*)outp)[(size_t)m * 2048 + n] = f2bf(val);
            } else if constexpr (OUTMODE == 1) {
                ((float*)outp)[(size_t)m * 2048 + n] = val;
            } else {
                int b = m >> 11, s = m & 2047;
                ((u16*)outp)[((size_t)b * 2048 + n) * 2048 + s] = f2bf(val);
            }
        }
    }
}

// ---------------------------------------------------------------------------
// In-place radix-2 DIT FFT over 2048 complex points in LDS (input bit-reversed)
// ---------------------------------------------------------------------------
__device__ __forceinline__ void fft_stages(float* re, float* im, int tid) {
#pragma unroll 1
    for (int lh = 0; lh < 11; ++lh) {
        const int half = 1 << lh;
        const float angs = -PI_F / (float)half;
        __syncthreads();
#pragma unroll
        for (int u = 0; u < 4; ++u) {
            int bidx = tid + u * 256;           // 0..1023
            int j = bidx & (half - 1);
            int i0 = ((bidx >> lh) << (lh + 1)) | j;
            int i1 = i0 + half;
            float wr, wi;
            __sincosf(angs * (float)j, &wi, &wr);
            float xr = re[i1], xi = im[i1];
            float tr = wr * xr - wi * xi;
            float ti = wr * xi + wi * xr;
            float yr = re[i0], yi = im[i0];
            re[i1] = yr - tr; im[i1] = yi - ti;
            re[i0] = yr + tr; im[i0] = yi + ti;
        }
    }
    __syncthreads();
}

// ---------------------------------------------------------------------------
// Spectral attention: one block per (b, channel). Qt/Kt/Vt are [B][2048][2048]
// bf16 (time along s, contiguous). Writes attn_w * V in place over Vt.
// ---------------------------------------------------------------------------
__global__ __launch_bounds__(256) void spectral_k(const u16* __restrict__ Qt,
                                                  const u16* __restrict__ Kt,
                                                  u16* __restrict__ Vt,
                                                  const float* __restrict__ alpha) {
    __shared__ float qre[2048], qim[2048], kre[2048], kim[2048];
    const int tid = threadIdx.x;
    const int c = blockIdx.x & 2047;
    const int b = blockIdx.x >> 11;
    const size_t base = ((size_t)b * 2048 + c) * 2048;
    const float ac = alpha[c];

    for (int s = tid; s < 2048; s += 256) {
        int r = __brev((unsigned)s) >> 21;
        qre[r] = bf2f(Qt[base + s]); qim[r] = 0.f;
        kre[r] = bf2f(Kt[base + s]); kim[r] = 0.f;
    }
    fft_stages(qre, qim, tid);   // starts with __syncthreads()
    fft_stages(kre, kim, tid);

    float pr[8], pi[8];
#pragma unroll
    for (int u = 0; u < 8; ++u) {
        int k = tid + u * 256;
        float qr = qre[k], qi2 = qim[k], kr = kre[k], ki = kim[k];
        float cr = qr * kr + qi2 * ki;          // Qf * conj(Kf)
        float ci = qi2 * kr - qr * ki;
        int kk = min(k, 2048 - k);
        float f = (float)kk * (1.0f / 2048.0f);
        float ph = atanf(__logf(f + 1e-6f));
        float fr, fi;
        __sincosf(ph * ac, &fi, &fr);           // filt = fr + i*fi
        pr[u] = cr * fr - ci * fi;
        pi[u] = -(cr * fi + ci * fr);           // conj -> inverse via forward FFT
    }
    __syncthreads();
#pragma unroll
    for (int u = 0; u < 8; ++u) {
        int k = tid + u * 256;
        int r = __brev((unsigned)k) >> 21;
        qre[r] = pr[u]; qim[r] = pi[u];
    }
    fft_stages(qre, qim, tid);

    for (int s = tid; s < 2048; s += 256) {
        float w = qre[s] * (1.0f / 2048.0f);    // Re(ifft)
        float v = bf2f(Vt[base + s]);
        Vt[base + s] = f2bf(w * v);
    }
}

// ---------------------------------------------------------------------------
// Transpose [B][C][S] bf16 -> [(b,s)][c] bf16
// ---------------------------------------------------------------------------
__global__ __launch_bounds__(256) void transpose_k(const u16* __restrict__ in,
                                                   u16* __restrict__ out) {
    __shared__ u16 tile[32][33];
    int b = blockIdx.z;
    int c0 = blockIdx.x * 32, s0 = blockIdx.y * 32;
    int tx = threadIdx.x, ty = threadIdx.y;     // 32 x 8
#pragma unroll
    for (int dy = 0; dy < 32; dy += 8)
        tile[ty + dy][tx] = in[((size_t)b * 2048 + c0 + ty + dy) * 2048 + s0 + tx];
    __syncthreads();
#pragma unroll
    for (int dy = 0; dy < 32; dy += 8)
        out[((size_t)b * 2048 + s0 + ty + dy) * 2048 + c0 + tx] = tile[tx][ty + dy];
}

// ---------------------------------------------------------------------------
extern "C" void kernel_launch(void* const* d_in, const int* in_sizes, int n_in,
                              void* d_out, int out_size, void* d_ws, size_t ws_size,
                              hipStream_t stream) {
    const float* query = (const float*)d_in[0];
    const float* key   = (const float*)d_in[1];
    const float* value = (const float*)d_in[2];
    const float* Wq    = (const float*)d_in[3];
    const float* bq    = (const float*)d_in[4];
    const float* Wk    = (const float*)d_in[5];
    const float* bk    = (const float*)d_in[6];
    const float* Wv    = (const float*)d_in[7];
    const float* bv    = (const float*)d_in[8];
    const float* alpha = (const float*)d_in[9];
    const float* Wint  = (const float*)d_in[10];
    const float* bint  = (const float*)d_in[11];
    const float* Wfin  = (const float*)d_in[12];
    const float* bfin  = (const float*)d_in[13];
    const float* Wout  = (const float*)d_in[14];
    const float* bout  = (const float*)d_in[15];

    char* ws = (char*)d_ws;
    size_t off = 0;
    auto alloc = [&](size_t bytes) -> void* {
        void* p = ws + off;
        off += (bytes + 255) & ~(size_t)255;
        return p;
    };
    u16* Eq   = (u16*)alloc((size_t)2048 * 512 * 2);
    u16* Ek   = (u16*)alloc((size_t)2048 * 512 * 2);
    u16* Ev   = (u16*)alloc((size_t)2048 * 512 * 2);
    u16* Eint = (u16*)alloc((size_t)2048 * 2048 * 2);
    u16* Efin = (u16*)alloc((size_t)2048 * 2048 * 2);
    u16* Eout = (u16*)alloc((size_t)2048 * 2048 * 2);
    u16* Qt   = (u16*)alloc((size_t)4 * 2048 * 2048 * 2);  // [B][C][S]
    u16* Kt   = (u16*)alloc((size_t)4 * 2048 * 2048 * 2);
    u16* Vt   = (u16*)alloc((size_t)4 * 2048 * 2048 * 2);  // becomes attn^T
    u16* attn = (u16*)alloc((size_t)8192 * 2048 * 2);      // [(b,s)][c]
    u16* h1   = Qt;  // reuse
    u16* h2   = Kt;  // reuse

    // Expand quaternion weights
    build_E<<<(2048 * 512  + 255) / 256, 256, 0, stream>>>(Wq,   Eq,   9);
    build_E<<<(2048 * 512  + 255) / 256, 256, 0, stream>>>(Wk,   Ek,   9);
    build_E<<<(2048 * 512  + 255) / 256, 256, 0, stream>>>(Wv,   Ev,   9);
    build_E<<<(2048 * 2048 + 255) / 256, 256, 0, stream>>>(Wint, Eint, 11);
    build_E<<<(2048 * 2048 + 255) / 256, 256, 0, stream>>>(Wfin, Efin, 11);
    build_E<<<(2048 * 2048 + 255) / 256, 256, 0, stream>>>(Wout, Eout, 11);

    dim3 g1(32, 128);  // N/64, M/64
    // Q/K/V projections, output transposed [b][c][s] bf16
    gemm_k<512, true, 2><<<g1, 256, 0, stream>>>(query, Eq, bq, Qt);
    gemm_k<512, true, 2><<<g1, 256, 0, stream>>>(key,   Ek, bk, Kt);
    gemm_k<512, true, 2><<<g1, 256, 0, stream>>>(value, Ev, bv, Vt);

    // FFT correlation + spectral filter + V multiply (in place over Vt)
    spectral_k<<<8192, 256, 0, stream>>>(Qt, Kt, Vt, alpha);

    // attn^T -> attn [(b,s)][c]
    dim3 gt(64, 64, 4);
    transpose_k<<<gt, dim3(32, 8), 0, stream>>>(Vt, attn);

    // Three mid/out quaternion linears
    gemm_k<2048, false, 0><<<g1, 256, 0, stream>>>(attn, Eint, bint, h1);
    gemm_k<2048, false, 0><<<g1, 256, 0, stream>>>(h1,   Efin, bfin, h2);
    gemm_k<2048, false, 1><<<g1, 256, 0, stream>>>(h2,   Eout, bout, (float*)d_out);
}

// Round 2
// 522.770 us; speedup vs baseline: 2.1738x; 2.1738x over previous
//
#include <hip/hip_runtime.h>
#include <hip/hip_bf16.h>
#include <cstdint>

typedef unsigned short u16;
typedef u16  u16x8 __attribute__((ext_vector_type(8)));
typedef short s16x8 __attribute__((ext_vector_type(8)));
typedef float f32x4 __attribute__((ext_vector_type(4)));

#define PI_F 3.14159265358979323846f
#define PD(i) ((i) + ((i) >> 5))

static __device__ __forceinline__ u16 f2bf(float f) {
    union { float f; unsigned u; } v; v.f = f;
    unsigned r = v.u + 0x7fffu + ((v.u >> 16) & 1u);
    return (u16)(r >> 16);
}
static __device__ __forceinline__ float bf2f(u16 h) {
    union { unsigned u; float f; } v; v.u = ((unsigned)h) << 16;
    return v.f;
}

__device__ __forceinline__ void gl_lds16(const u16* g, u16* l) {
    __builtin_amdgcn_global_load_lds(
        (const __attribute__((address_space(1))) unsigned int*)g,
        (__attribute__((address_space(3))) unsigned int*)l, 16, 0, 0);
}

// ---------------------------------------------------------------------------
// f32 -> bf16 convert (vectorized)
// ---------------------------------------------------------------------------
__global__ __launch_bounds__(256) void cvt_bf16(const float* __restrict__ in,
                                                u16* __restrict__ out, int n8) {
    int i = blockIdx.x * 256 + threadIdx.x;
    if (i >= n8) return;
    float4 a = ((const float4*)in)[2 * i];
    float4 b = ((const float4*)in)[2 * i + 1];
    u16x8 v;
    v[0] = f2bf(a.x); v[1] = f2bf(a.y); v[2] = f2bf(a.z); v[3] = f2bf(a.w);
    v[4] = f2bf(b.x); v[5] = f2bf(b.y); v[6] = f2bf(b.z); v[7] = f2bf(b.w);
    ((u16x8*)out)[i] = v;
}

// ---------------------------------------------------------------------------
// Expand quaternion weight W[4][512][in_q] into real matrix E[2048][4*in_q] bf16
// ---------------------------------------------------------------------------
__global__ void build_E(const float* __restrict__ W, u16* __restrict__ E, int logK) {
    const int K = 1 << logK;
    int idx = blockIdx.x * 256 + threadIdx.x;
    if (idx >= (2048 << logK)) return;
    int n = idx >> logK, k = idx & (K - 1);
    int o = n >> 2, c = n & 3, i = k >> 2, cp = k & 3;
    const int   qm[4][4] = {{0,1,2,3},{1,0,3,2},{2,3,0,1},{3,2,1,0}};
    const float qs[4][4] = {{1.f,-1.f,-1.f,-1.f},{1.f,1.f,1.f,-1.f},
                            {1.f,-1.f,1.f,1.f},{1.f,1.f,-1.f,1.f}};
    int in_q = K >> 2;
    float w = W[(size_t)qm[c][cp] * 512 * in_q + (size_t)o * in_q + i] * qs[c][cp];
    E[idx] = f2bf(w);
}

// ---------------------------------------------------------------------------
// bf16 MFMA GEMM (m97 structure): out[8192][2048] = A[M][K] * E[N][K]^T + bias
// 128x128 tile, BK=64, 4 waves (2x2), each wave 64x64 = 4x4 frags 16x16x32.
// global_load_lds 16B direct staging; T2 swizzle slot^=row&7 both sides.
// OUTMODE 0: bf16 [m][n]; 1: f32 [m][n]; 2: bf16 transposed [b][n][s]
// ---------------------------------------------------------------------------
template<int K, int OUTMODE>
__global__ __launch_bounds__(256) void gemm2(const u16* __restrict__ A,
                                             const u16* __restrict__ E,
                                             const float* __restrict__ bias,
                                             void* __restrict__ outp) {
    __shared__ u16 As[128 * 64];
    __shared__ u16 Bs[128 * 64];
    const int t    = threadIdx.x;
    const int lane = t & 63, wave = t >> 6;
    const int wr   = wave >> 1, wc = wave & 1;
    const int lr   = lane & 15, kg = lane >> 4;
    const int l7   = lr & 7;
    const int m0   = blockIdx.y * 128;
    const int n0   = blockIdx.x * 128;

    f32x4 acc[4][4];
#pragma unroll
    for (int i = 0; i < 4; ++i)
#pragma unroll
        for (int j = 0; j < 4; ++j) acc[i][j] = (f32x4){0.f, 0.f, 0.f, 0.f};

    const int arow = wr * 64 + lr;
    const int brow = wc * 64 + lr;

    for (int k0 = 0; k0 < K; k0 += 64) {
#pragma unroll
        for (int c = 0; c < 4; ++c) {
            int idx = t + c * 256;
            int row = idx >> 3, sl = idx & 7;
            int gsl = sl ^ (row & 7);          // inverse-swizzled global source
            gl_lds16(A + (size_t)(m0 + row) * K + k0 + gsl * 8, &As[idx * 8]);
            gl_lds16(E + (size_t)(n0 + row) * K + k0 + gsl * 8, &Bs[idx * 8]);
        }
        __syncthreads();
#pragma unroll
        for (int ks = 0; ks < 2; ++ks) {
            const int slot = (ks * 4 + kg) ^ l7;   // swizzled read slot
            s16x8 av[4], bv[4];
#pragma unroll
            for (int mi = 0; mi < 4; ++mi)
                av[mi] = *(const s16x8*)&As[(arow + mi * 16) * 64 + slot * 8];
#pragma unroll
            for (int ni = 0; ni < 4; ++ni)
                bv[ni] = *(const s16x8*)&Bs[(brow + ni * 16) * 64 + slot * 8];
#pragma unroll
            for (int mi = 0; mi < 4; ++mi)
#pragma unroll
                for (int ni = 0; ni < 4; ++ni)
                    acc[mi][ni] = __builtin_amdgcn_mfma_f32_16x16x32_bf16(
                        av[mi], bv[ni], acc[mi][ni], 0, 0, 0);
        }
        __syncthreads();
    }

#pragma unroll
    for (int ni = 0; ni < 4; ++ni) {
        int n = n0 + wc * 64 + ni * 16 + lr;
        float bvl = bias[n];
#pragma unroll
        for (int mi = 0; mi < 4; ++mi) {
#pragma unroll
            for (int r = 0; r < 4; ++r) {
                int m = m0 + wr * 64 + mi * 16 + kg * 4 + r;
                float val = acc[mi][ni][r] + bvl;
                if constexpr (OUTMODE == 0) {
                    ((u16*)outp)[(size_t)m * 2048 + n] = f2bf(val);
                } else if constexpr (OUTMODE == 1) {
                    ((float*)outp)[(size_t)m * 2048 + n] = val;
                } else {
                    int b = m >> 11, s = m & 2047;
                    ((u16*)outp)[((size_t)b * 2048 + n) * 2048 + s] = f2bf(val);
                }
            }
        }
    }
}

// ---------------------------------------------------------------------------
// In-place radix-2 DIT FFT, 2048 complex in padded LDS (input bit-reversed).
// Twiddles hoisted (1 sincos/stage) for stages 0..8.
// ---------------------------------------------------------------------------
__device__ __forceinline__ void bfly(float* re, float* im, int i0, int i1,
                                     float wr, float wi) {
    int p0 = PD(i0), p1 = PD(i1);
    float xr = re[p1], xi = im[p1];
    float tr = wr * xr - wi * xi;
    float ti = wr * xi + wi * xr;
    float yr = re[p0], yi = im[p0];
    re[p1] = yr - tr; im[p1] = yi - ti;
    re[p0] = yr + tr; im[p0] = yi + ti;
}

__device__ void fft2048(float* re, float* im, int t) {
#pragma unroll 1
    for (int lh = 0; lh < 9; ++lh) {
        const int half = 1 << lh;
        int j = t & (half - 1);
        float wr, wi;
        __sincosf((-PI_F / (float)half) * (float)j, &wi, &wr);
        __syncthreads();
#pragma unroll
        for (int u = 0; u < 4; ++u) {
            int bidx = t + u * 256;
            int i0 = ((bidx >> lh) << (lh + 1)) | j;
            bfly(re, im, i0, i0 + half, wr, wi);
        }
    }
#pragma unroll 1
    for (int lh = 9; lh < 11; ++lh) {
        const int half = 1 << lh;
        __syncthreads();
#pragma unroll
        for (int u = 0; u < 4; ++u) {
            int bidx = t + u * 256;
            int j = bidx & (half - 1);
            int i0 = ((bidx >> lh) << (lh + 1)) | j;
            float wr, wi;
            __sincosf((-PI_F / (float)half) * (float)j, &wi, &wr);
            bfly(re, im, i0, i0 + half, wr, wi);
        }
    }
    __syncthreads();
}

// ---------------------------------------------------------------------------
// Spectral attention v2: 2 channels/block, Q+iK packed forward FFTs (2),
// Hermitian-packed inverse (1). Vt multiplied in place.
// ---------------------------------------------------------------------------
__global__ __launch_bounds__(256) void spectral2(const u16* __restrict__ Qt,
                                                 const u16* __restrict__ Kt,
                                                 u16* __restrict__ Vt,
                                                 const float* __restrict__ alpha) {
    __shared__ float zre[2112], zim[2112];
    const int t  = threadIdx.x;
    const int b  = blockIdx.x >> 10;
    const int cp = blockIdx.x & 1023;
    const int c0 = cp * 2;
    const size_t base0 = ((size_t)b * 2048 + c0) * 2048;
    const size_t base1 = base0 + 2048;

    float ph[4];
    float PH1r[4], PH1i[4], PH2r[4], PH2i[4];
    float ph24 = 0.f, PH24_1 = 0.f, PH24_2 = 0.f;   // index-1024 self-pair (t==0)

#pragma unroll
    for (int ch = 0; ch < 2; ++ch) {
        const size_t base = ch ? base1 : base0;
        const u16* Qp = Qt + base;
        const u16* Kp = Kt + base;
        __syncthreads();    // prior LDS consumers done before overwrite
#pragma unroll
        for (int u = 0; u < 8; ++u) {
            int s = t + u * 256;
            int r = __brev((unsigned)s) >> 21;
            zre[PD(r)] = bf2f(Qp[s]);
            zim[PD(r)] = bf2f(Kp[s]);
        }
        fft2048(zre, zim, t);
        const float ac = alpha[c0 + ch];
#pragma unroll
        for (int u = 0; u < 4; ++u) {
            int k = t + u * 256;
            int m = (2048 - k) & 2047;
            float ar = zre[PD(k)], ai = zim[PD(k)];
            float br = zre[PD(m)], bi = zim[PD(m)];
            // unpack: Qf = (Z[k]+conj(Z[m]))/2 ; Kf = (Z[k]-conj(Z[m]))/(2i)
            float qr = 0.5f * (ar + br), qi = 0.5f * (ai - bi);
            float kr = 0.5f * (ai + bi), ki = 0.5f * (br - ar);
            float cr = qr * kr + qi * ki;      // Qf*conj(Kf)
            float ci = qi * kr - qr * ki;
            if (ch == 0) {
                int kk = min(k, 2048 - k);
                ph[u] = atanf(__logf((float)kk * (1.0f / 2048.0f) + 1e-6f));
            }
            float fr, fi;
            __sincosf(ph[u] * ac, &fi, &fr);
            float Pkr = cr * fr - ci * fi, Pki = cr * fi + ci * fr;
            // mirror index m
            float qr2 = 0.5f * (br + ar), qi2 = 0.5f * (bi - ai);
            float kr2 = 0.5f * (bi + ai), ki2 = 0.5f * (ar - br);
            float cr2 = qr2 * kr2 + qi2 * ki2;
            float ci2 = qi2 * kr2 - qr2 * ki2;
            float Pmr = cr2 * fr - ci2 * fi, Pmi = cr2 * fi + ci2 * fr;
            // Hermitian projection: P_H[k] = (P[k]+conj(P[m]))/2 ; P_H[m]=conj
            float hr = 0.5f * (Pkr + Pmr), hi = 0.5f * (Pki - Pmi);
            if (ch == 0) { PH1r[u] = hr; PH1i[u] = hi; }
            else         { PH2r[u] = hr; PH2i[u] = hi; }
        }
        if (t == 0) {   // index 1024 self-pair
            float ar = zre[PD(1024)], ai = zim[PD(1024)];
            float cr = ar * ai;                 // Qf=ar, Kf=ai (both real)
            if (ch == 0) ph24 = atanf(__logf(0.5f + 1e-6f));
            float fr, fi;
            __sincosf(ph24 * ac, &fi, &fr);
            if (ch == 0) PH24_1 = cr * fr; else PH24_2 = cr * fr;
        }
    }

    __syncthreads();   // all extraction reads complete
    // Y = P1_H + i*P2_H, written bit-reversed; Y[m] uses conj relations
#pragma unroll
    for (int u = 0; u < 4; ++u) {
        int k = t + u * 256;
        int m = (2048 - k) & 2047;
        int rk = __brev((unsigned)k) >> 21;
        int rm = __brev((unsigned)m) >> 21;
        zre[PD(rk)] = PH1r[u] - PH2i[u];
        zim[PD(rk)] = PH1i[u] + PH2r[u];
        zre[PD(rm)] = PH1r[u] + PH2i[u];
        zim[PD(rm)] = PH2r[u] - PH1i[u];
    }
    if (t == 0) {      // rev(1024) = 1
        zre[PD(1)] = PH24_1;
        zim[PD(1)] = PH24_2;
    }
    fft2048(zre, zim, t);

    // ifft(Y)[s] = fft(Y)[(N-s)%N]/N ; Re->ch0 weights, Im->ch1 weights
#pragma unroll
    for (int u = 0; u < 8; ++u) {
        int s = t + u * 256;
        int j = (2048 - s) & 2047;
        float w0 = zre[PD(j)] * (1.0f / 2048.0f);
        float w1 = zim[PD(j)] * (1.0f / 2048.0f);
        Vt[base0 + s] = f2bf(bf2f(Vt[base0 + s]) * w0);
        Vt[base1 + s] = f2bf(bf2f(Vt[base1 + s]) * w1);
    }
}

// ---------------------------------------------------------------------------
// Transpose [B][C][S] bf16 -> [(b,s)][c] bf16
// ---------------------------------------------------------------------------
__global__ __launch_bounds__(256) void transpose_k(const u16* __restrict__ in,
                                                   u16* __restrict__ out) {
    __shared__ u16 tile[32][33];
    int b = blockIdx.z;
    int c0 = blockIdx.x * 32, s0 = blockIdx.y * 32;
    int tx = threadIdx.x, ty = threadIdx.y;
#pragma unroll
    for (int dy = 0; dy < 32; dy += 8)
        tile[ty + dy][tx] = in[((size_t)b * 2048 + c0 + ty + dy) * 2048 + s0 + tx];
    __syncthreads();
#pragma unroll
    for (int dy = 0; dy < 32; dy += 8)
        out[((size_t)b * 2048 + s0 + ty + dy) * 2048 + c0 + tx] = tile[tx][ty + dy];
}

// ---------------------------------------------------------------------------
extern "C" void kernel_launch(void* const* d_in, const int* in_sizes, int n_in,
                              void* d_out, int out_size, void* d_ws, size_t ws_size,
                              hipStream_t stream) {
    const float* query = (const float*)d_in[0];
    const float* key   = (const float*)d_in[1];
    const float* value = (const float*)d_in[2];
    const float* Wq    = (const float*)d_in[3];
    const float* bq    = (const float*)d_in[4];
    const float* Wk    = (const float*)d_in[5];
    const float* bk    = (const float*)d_in[6];
    const float* Wv    = (const float*)d_in[7];
    const float* bv    = (const float*)d_in[8];
    const float* alpha = (const float*)d_in[9];
    const float* Wint  = (const float*)d_in[10];
    const float* bint  = (const float*)d_in[11];
    const float* Wfin  = (const float*)d_in[12];
    const float* bfin  = (const float*)d_in[13];
    const float* Wout  = (const float*)d_in[14];
    const float* bout  = (const float*)d_in[15];

    char* ws = (char*)d_ws;
    size_t off = 0;
    auto alloc = [&](size_t bytes) -> void* {
        void* p = ws + off;
        off += (bytes + 255) & ~(size_t)255;
        return p;
    };
    u16* Eq   = (u16*)alloc((size_t)2048 * 512 * 2);
    u16* Ek   = (u16*)alloc((size_t)2048 * 512 * 2);
    u16* Ev   = (u16*)alloc((size_t)2048 * 512 * 2);
    u16* Eint = (u16*)alloc((size_t)2048 * 2048 * 2);
    u16* Efin = (u16*)alloc((size_t)2048 * 2048 * 2);
    u16* Eout = (u16*)alloc((size_t)2048 * 2048 * 2);
    u16* Qt   = (u16*)alloc((size_t)4 * 2048 * 2048 * 2);  // [B][C][S]
    u16* Kt   = (u16*)alloc((size_t)4 * 2048 * 2048 * 2);
    u16* Vt   = (u16*)alloc((size_t)4 * 2048 * 2048 * 2);
    u16* attn = (u16*)alloc((size_t)8192 * 2048 * 2);      // also hosts Aq/Ak/Av early
    u16* h1   = Qt;
    u16* h2   = Kt;
    // converted bf16 inputs live in the (not-yet-used) attn buffer
    u16* Aq = attn;
    u16* Ak = attn + (size_t)8192 * 512;
    u16* Av = attn + (size_t)8192 * 1024;

    const int n8 = 8192 * 512 / 8;
    cvt_bf16<<<(n8 + 255) / 256, 256, 0, stream>>>(query, Aq, n8);
    cvt_bf16<<<(n8 + 255) / 256, 256, 0, stream>>>(key,   Ak, n8);
    cvt_bf16<<<(n8 + 255) / 256, 256, 0, stream>>>(value, Av, n8);

    build_E<<<(2048 * 512  + 255) / 256, 256, 0, stream>>>(Wq,   Eq,   9);
    build_E<<<(2048 * 512  + 255) / 256, 256, 0, stream>>>(Wk,   Ek,   9);
    build_E<<<(2048 * 512  + 255) / 256, 256, 0, stream>>>(Wv,   Ev,   9);
    build_E<<<(2048 * 2048 + 255) / 256, 256, 0, stream>>>(Wint, Eint, 11);
    build_E<<<(2048 * 2048 + 255) / 256, 256, 0, stream>>>(Wfin, Efin, 11);
    build_E<<<(2048 * 2048 + 255) / 256, 256, 0, stream>>>(Wout, Eout, 11);

    dim3 g2(16, 64);   // N/128, M/128
    gemm2<512, 2><<<g2, 256, 0, stream>>>(Aq, Eq, bq, Qt);
    gemm2<512, 2><<<g2, 256, 0, stream>>>(Ak, Ek, bk, Kt);
    gemm2<512, 2><<<g2, 256, 0, stream>>>(Av, Ev, bv, Vt);

    spectral2<<<4096, 256, 0, stream>>>(Qt, Kt, Vt, alpha);

    dim3 gt(64, 64, 4);
    transpose_k<<<gt, dim3(32, 8), 0, stream>>>(Vt, attn);

    gemm2<2048, 0><<<g2, 256, 0, stream>>>(attn, Eint, bint, h1);
    gemm2<2048, 0><<<g2, 256, 0, stream>>>(h1,   Efin, bfin, h2);
    gemm2<2048, 1><<<g2, 256, 0, stream>>>(h2,   Eout, bout, (float*)d_out);
}